// Round 5
// baseline (706.624 us; speedup 1.0000x reference)
//
#include <hip/hip_runtime.h>

// DeformableSliceGrouped on MI355X — R9: tail vectorization (I/O is bf16).
//   kA_mfma: R8 structure (512 thr, 8 waves, 32KB LDS, hi-only B) +
//            ushort4 staging loads on the bf16 path.
//   kB_mix:  wave-zo-split (4 waves x 8 zo), lane owns 2 hw -> float2 u-loads,
//            packed u32 bf16 stores, L1-shared u reads across waves.
//   k5:      ushort4 bf16 path.
//   probe:   ref parallelized across 256 threads via LDS handoff.
//   fallback: single merged dispatch (runtime dtype flag).

#define B_   2
#define C_   256
#define Z_   32
#define HW_  2304
#define NSP  73728        // Z_*HW_
#define NBN  147456.0f    // B_*Z_*HW_

typedef unsigned short u16;
typedef unsigned int   u32;
typedef __attribute__((ext_vector_type(8))) short bf16x8;
typedef __attribute__((ext_vector_type(4))) float f32x4;

// ---- module-global scratch (d_ws is never used) ----
__device__ int   g_isf32;
__device__ int   g_use_mfma;
__device__ float g_pe[Z_ * C_];
__device__ __align__(16) float g_wt[C_ * 512];      // [c][row]: 0..255 w2, 256..511 q_w
__device__ __align__(16) u16   g_afrag[32 * 8 * 2 * 64 * 8];  // 512 KB packed A-frags
__device__ int   g_qmax[B_ * Z_ * C_];
__device__ __align__(16) float g_Mt[B_ * Z_ * Z_];  // [b][y][zo]
__device__ float g_bn_sum[C_];
__device__ float g_bn_ssq[C_];
__device__ float g_u[(size_t)B_ * C_ * NSP];        // 151 MB fp32: u = w2 @ (f+pe)

__device__ __forceinline__ u16 f2bf(float f) {
  u32 x = __float_as_uint(f);
  x = x + 0x7fffu + ((x >> 16) & 1u);   // RNE
  return (u16)(x >> 16);
}
__device__ __forceinline__ float bf2f(u16 h) {
  return __uint_as_float(((u32)h) << 16);
}
__device__ __forceinline__ float ldx(const void* p, size_t i, int f32) {
  if (f32) return ((const float*)p)[i];
  return __uint_as_float(((u32)((const u16*)p)[i]) << 16);
}
__device__ __forceinline__ void stx(void* p, size_t i, int f32, float v) {
  if (f32) ((float*)p)[i] = v;
  else     ((u16*)p)[i] = f2bf(v);
}
__device__ __forceinline__ int f2key(float f) {
  int b = __float_as_int(f);
  return b >= 0 ? b : (b ^ 0x7fffffff);
}
__device__ __forceinline__ float key2f(int k) {
  int b = k >= 0 ? k : (k ^ 0x7fffffff);
  return __int_as_float(b);
}
__device__ __forceinline__ float sane(float v) {
  u32 a = __float_as_uint(v) & 0x7fffffffu;
  return (a >= 0x7f800000u) ? 0.f : v;
}
__device__ __forceinline__ float wredmax(float m) {
  m = fmaxf(m, __shfl_xor(m, 1));  m = fmaxf(m, __shfl_xor(m, 2));
  m = fmaxf(m, __shfl_xor(m, 4));  m = fmaxf(m, __shfl_xor(m, 8));
  m = fmaxf(m, __shfl_xor(m, 16)); m = fmaxf(m, __shfl_xor(m, 32));
  return m;
}
__device__ __forceinline__ float wredsum(float s) {
  s += __shfl_xor(s, 1);  s += __shfl_xor(s, 2);  s += __shfl_xor(s, 4);
  s += __shfl_xor(s, 8);  s += __shfl_xor(s, 16); s += __shfl_xor(s, 32);
  return s;
}

// ================= MFMA shared primitives (probe AND main kernel) ==========
// LDS: n-major XOR-swizzled, hi plane only (32 KB):
//   byte(n,k) = n*512 + k*2, XOR ((n&15)<<4)          [R6/R8 HW-verified]
// 512 threads: wave w(0..7), lane l: k = r*32 + w*4 + (l>>4), n = (l&15)*4+0..3

__device__ __forceinline__ void stage_x(const void* __restrict__ f, int f32,
                                        int b, int z, int ncol0, u16* xs) {
  const int tid = threadIdx.x;
  const int w = tid >> 6, l = tid & 63;
  const int n0 = (l & 15) * 4;
  const int g = l >> 4;
#pragma unroll
  for (int r = 0; r < 8; ++r) {
    const int k = r * 32 + w * 4 + g;
    const float pv = g_pe[z * C_ + k];
    const size_t fe = (size_t)(b * C_ + k) * NSP + ncol0 + n0;
    float x0, x1, x2, x3;
    if (f32) {
      const float4 v = *(const float4*)((const float*)f + fe);
      x0 = v.x; x1 = v.y; x2 = v.z; x3 = v.w;
    } else {
      const ushort4 v = *(const ushort4*)((const u16*)f + fe);   // 8B coalesced
      x0 = bf2f(v.x); x1 = bf2f(v.y); x2 = bf2f(v.z); x3 = bf2f(v.w);
    }
    x0 += pv; x1 += pv; x2 += pv; x3 += pv;
#pragma unroll
    for (int e = 0; e < 4; ++e) {
      const float xv = (e == 0) ? x0 : (e == 1) ? x1 : (e == 2) ? x2 : x3;
      const int n = n0 + e;
      u32 byte = (u32)n * 512u + (u32)k * 2u;
      byte ^= (u32)(n & 15) << 4;
      xs[byte >> 1] = f2bf(xv);
    }
  }
}

// B fragment: lane l supplies B[k = kk*32 + 8*(l>>4) + i][n = j*16 + (l&15)].
__device__ __forceinline__ bf16x8 read_bfrag(const u16* xs, int j, int kk, int lane) {
  const int n = j * 16 + (lane & 15);
  u32 byte = (u32)n * 512u + (u32)kk * 64u + (u32)(lane >> 4) * 16u;
  byte ^= (u32)(n & 15) << 4;
  return *(const bf16x8*)(const void*)((const char*)xs + byte);
}

__device__ __forceinline__ bf16x8 load_afrag(int rs, int kk, int plane, int lane) {
  const size_t off = ((((size_t)(rs * 8 + kk) * 2 + plane) * 64 + lane) * 8);
  return *(const bf16x8*)(const void*)(g_afrag + off);
}

// ------------------------------------------------ K00: input dtype detector
__global__ void k00_detect(const void* f) {
  const int t = threadIdx.x;
  u32 w = ((const u32*)f)[(size_t)t * 9973u];
  u32 e = (w >> 7) & 0xFFu;
  int in = (e >= 90u && e <= 140u) ? 1 : 0;
  for (int o = 1; o < 64; o <<= 1) in += __shfl_xor(in, o);
  if (t == 0) g_isf32 = (in < 40) ? 1 : 0;
}

// ------------------------------------------------ K0: setup
__device__ __forceinline__ void pack_afrag(int row, int k, float val) {
  const int rs = row >> 4, kk = k >> 5, i = k & 7, g = (k >> 3) & 3;
  const int l = (row & 15) | (g << 4);
  u16 hi = f2bf(val);
  u16 lo = f2bf(val - bf2f(hi));
  const size_t u = (((size_t)(rs * 8 + kk) * 2) * 64 + l) * 8 + i;
  g_afrag[u] = hi;
  g_afrag[u + 512] = lo;   // plane offset = 64*8 u16
}

__global__ __launch_bounds__(256) void k0_setup(const void* o_w, const void* v_w,
                                                const void* q_w) {
  const int f32 = g_isf32;
  const int blk = blockIdx.x, t = threadIdx.x;
  if (blk < 256) {
    float acc = 0.f;
    for (int c = 0; c < 256; ++c)
      acc += ldx(o_w, (size_t)blk * 256 + c, f32) * ldx(v_w, (size_t)c * 256 + t, f32);
    g_wt[(size_t)t * 512 + blk] = acc;
    const float qv = ldx(q_w, (size_t)blk * 256 + t, f32);
    g_wt[(size_t)t * 512 + 256 + blk] = qv;
    pack_afrag(blk, t, acc);          // rows 0..255 = w2
    pack_afrag(256 + blk, t, qv);     // rows 256..511 = q_w
  } else {
    const int ch = t;
    const float divf = expf(-(float)(ch >> 1) * (9.210340371976184f / 128.0f));
    for (int z = 0; z < Z_; ++z) {
      float arg = (float)z * divf;
      g_pe[z * 256 + ch] = (ch & 1) ? cosf(arg) : sinf(arg);
    }
    const int init_key = f2key(-1e30f);
    for (int k = t; k < B_ * Z_ * 256; k += 256) g_qmax[k] = init_key;
    g_bn_sum[t] = 0.f;
    g_bn_ssq[t] = 0.f;
  }
}

// ------------------------------------------------ KP: MFMA layout probe
// Stage real tile with production primitives; MFMA one 16x16 tile; all 256
// threads verify one element each vs fp32 VALU reference.
__global__ __launch_bounds__(512) void kP_probe(const void* __restrict__ f) {
  __shared__ u16 xs[16384];
  __shared__ float smacc[64][4];
  __shared__ int s_ok;
  const int f32 = g_isf32;
  if (threadIdx.x == 0) s_ok = 1;
  stage_x(f, f32, 0, 0, 0, xs);
  __syncthreads();
  if (threadIdx.x < 64) {
    const int lane = threadIdx.x;
    f32x4 acc = {0.f, 0.f, 0.f, 0.f};
    for (int kk = 0; kk < 8; ++kk) {
      bf16x8 bh = read_bfrag(xs, 0, kk, lane);
      bf16x8 ah = load_afrag(0, kk, 0, lane);
      bf16x8 al = load_afrag(0, kk, 1, lane);
      acc = __builtin_amdgcn_mfma_f32_16x16x32_bf16(ah, bh, acc, 0, 0, 0);
      acc = __builtin_amdgcn_mfma_f32_16x16x32_bf16(al, bh, acc, 0, 0, 0);
    }
#pragma unroll
    for (int reg = 0; reg < 4; ++reg) smacc[lane][reg] = acc[reg];
  }
  __syncthreads();
  if (threadIdx.x < 256) {
    const int l = threadIdx.x & 63, reg = threadIdx.x >> 6;
    const int col = l & 15;
    const int row = (l >> 4) * 4 + reg;   // rows 0..15 (w2)
    float r0 = 0.f, r1 = 0.f, r2 = 0.f, r3 = 0.f;
    for (int k = 0; k < 256; k += 4) {
      r0 = fmaf(g_wt[(size_t)(k+0) * 512 + row],
                ldx(f, (size_t)(k+0) * NSP + col, f32) + g_pe[k+0], r0);
      r1 = fmaf(g_wt[(size_t)(k+1) * 512 + row],
                ldx(f, (size_t)(k+1) * NSP + col, f32) + g_pe[k+1], r1);
      r2 = fmaf(g_wt[(size_t)(k+2) * 512 + row],
                ldx(f, (size_t)(k+2) * NSP + col, f32) + g_pe[k+2], r2);
      r3 = fmaf(g_wt[(size_t)(k+3) * 512 + row],
                ldx(f, (size_t)(k+3) * NSP + col, f32) + g_pe[k+3], r3);
    }
    float ref = (r0 + r1) + (r2 + r3);
    if (!(fabsf(smacc[l][reg] - ref) <= 0.02f + 0.01f * fabsf(ref)))
      atomicAnd(&s_ok, 0);
  }
  __syncthreads();
  if (threadIdx.x == 0) g_use_mfma = s_ok;
}

// ------------------------------------------------ KA-MFMA: fused dual GEMM
// 2304 blocks x 512 threads = b(2) * z(32) * nchunk(36).  Block: 512 rows x 64 n.
// Wave w (0..7) owns rs = w*4..w*4+3.  w<4 -> u rows (store); w>=4 -> q (maxpool).
__global__ __launch_bounds__(512, 4) void kA_mfma(const void* __restrict__ f) {
  if (!g_use_mfma) return;
  __shared__ u16 xs[16384];          // 32 KB: n-major XOR-swizzled x (hi plane)
  const int f32 = g_isf32;
  const int id = blockIdx.x;
  const int b = id / 1152;
  const int r2 = id % 1152;
  const int z = r2 / 36;
  const int m = r2 % 36;
  const int ncol0 = z * HW_ + m * 64;
  const int tid = threadIdx.x, w = tid >> 6, lane = tid & 63;

  stage_x(f, f32, b, z, ncol0, xs);
  __syncthreads();

  f32x4 acc[4][4];
  const f32x4 z4 = {0.f, 0.f, 0.f, 0.f};
#pragma unroll
  for (int r = 0; r < 4; ++r)
#pragma unroll
    for (int j = 0; j < 4; ++j) acc[r][j] = z4;

#pragma unroll 2
  for (int kk = 0; kk < 8; ++kk) {
    bf16x8 bh[4];
#pragma unroll
    for (int j = 0; j < 4; ++j) bh[j] = read_bfrag(xs, j, kk, lane);
#pragma unroll
    for (int rsl = 0; rsl < 4; ++rsl) {
      const int rs = w * 4 + rsl;
      bf16x8 ah = load_afrag(rs, kk, 0, lane);
      bf16x8 al = load_afrag(rs, kk, 1, lane);
#pragma unroll
      for (int j = 0; j < 4; ++j) {
        acc[rsl][j] = __builtin_amdgcn_mfma_f32_16x16x32_bf16(ah, bh[j], acc[rsl][j], 0, 0, 0);
        acc[rsl][j] = __builtin_amdgcn_mfma_f32_16x16x32_bf16(al, bh[j], acc[rsl][j], 0, 0, 0);
      }
    }
  }

  if (w < 4) {
#pragma unroll
    for (int rsl = 0; rsl < 4; ++rsl)
#pragma unroll
      for (int j = 0; j < 4; ++j)
#pragma unroll
        for (int reg = 0; reg < 4; ++reg) {
          const int row = (w * 4 + rsl) * 16 + (lane >> 4) * 4 + reg;
          g_u[(size_t)(b * C_ + row) * NSP + ncol0 + j * 16 + (lane & 15)] =
              acc[rsl][j][reg];
        }
  } else {
    const int rbase = (b * Z_ + z) * C_;
#pragma unroll
    for (int rsl = 0; rsl < 4; ++rsl)
#pragma unroll
      for (int reg = 0; reg < 4; ++reg) {
        float v = fmaxf(fmaxf(acc[rsl][0][reg], acc[rsl][1][reg]),
                        fmaxf(acc[rsl][2][reg], acc[rsl][3][reg]));
        v = fmaxf(v, __shfl_xor(v, 1));
        v = fmaxf(v, __shfl_xor(v, 2));
        v = fmaxf(v, __shfl_xor(v, 4));
        v = fmaxf(v, __shfl_xor(v, 8));
        if ((lane & 15) == 0)
          atomicMax(&g_qmax[rbase + ((w - 4) * 4 + rsl) * 16 + (lane >> 4) * 4 + reg],
                    f2key(v));
      }
  }
}

// ------------------------------------------------ KA-VALU: fallback (proven R5)
__global__ __launch_bounds__(256) void kA_gemm(const void* __restrict__ f) {
  if (g_use_mfma) return;
  const int f32 = g_isf32;
  const int bid = blockIdx.x;
  const int k  = bid & 7;
  const int jj = bid >> 3;
  const int T  = k + 8 * (jj >> 3);
  const int g  = jj & 7;
  const int b  = T / 288;
  const int tz = T % 288;
  const int z  = tz / 9;
  const int hc = tz % 9;
  const int t  = threadIdx.x;
  const int n_in_z = hc * 256 + t;
  const size_t fbase = (size_t)(b * C_) * NSP + (size_t)z * HW_ + n_in_z;

  float acc[64];
#pragma unroll
  for (int i = 0; i < 64; ++i) acc[i] = 0.f;

  const float* __restrict__ wtb = g_wt + g * 64;
  const float* __restrict__ pez = g_pe + z * C_;
  for (int c = 0; c < 256; ++c) {
    float fv = ldx(f, fbase + (size_t)c * NSP, f32) + pez[c];
    const float4* __restrict__ w4 = (const float4*)(wtb + (size_t)c * 512);
#pragma unroll
    for (int q = 0; q < 16; ++q) {
      float4 wv = w4[q];
      acc[4*q+0] = fmaf(wv.x, fv, acc[4*q+0]);
      acc[4*q+1] = fmaf(wv.y, fv, acc[4*q+1]);
      acc[4*q+2] = fmaf(wv.z, fv, acc[4*q+2]);
      acc[4*q+3] = fmaf(wv.w, fv, acc[4*q+3]);
    }
  }

  if (g < 4) {
    const size_t obase = (size_t)(b * C_ + g * 64) * NSP + (size_t)z * HW_ + n_in_z;
#pragma unroll
    for (int i = 0; i < 64; ++i)
      g_u[obase + (size_t)i * NSP] = acc[i];
  } else {
    const int rbase = (b * Z_ + z) * C_ + (g - 4) * 64;
#pragma unroll
    for (int i = 0; i < 64; ++i) {
      float mres = wredmax(acc[i]);
      if ((t & 63) == 0) atomicMax(&g_qmax[rbase + i], f2key(mres));
    }
  }
}

// ------------------------------------------------ K2: M build (tiny)
__global__ __launch_bounds__(64) void k2_mbuild(
    const void* offs_w, const void* offs_b,
    const void* attn_w, const void* attn_b) {
  const int f32 = g_isf32;
  const int bz = blockIdx.x;
  const int lane = threadIdx.x;
  float qp[4];
#pragma unroll
  for (int i = 0; i < 4; ++i)
    qp[i] = key2f(g_qmax[bz * 256 + lane * 4 + i]);

  float res[12];
  for (int p = 0; p < 12; ++p) {
    const void* wm = (p < 6) ? offs_w : attn_w;
    const size_t row = (size_t)(p < 6 ? p : p - 6) * 256;
    float s = 0.f;
#pragma unroll
    for (int i = 0; i < 4; ++i) s += qp[i] * ldx(wm, row + lane * 4 + i, f32);
    res[p] = sane(wredsum(s));
  }

  __shared__ float sm[Z_];
  if (lane < Z_) sm[lane] = 0.f;
  __syncthreads();
  if (lane == 0) {
    float att[6], mx = -1e30f;
#pragma unroll
    for (int p = 0; p < 6; ++p) {
      att[p] = sane(res[6 + p] + ldx(attn_b, p, f32));
      mx = fmaxf(mx, att[p]);
    }
    float den = 0.f;
#pragma unroll
    for (int p = 0; p < 6; ++p) { att[p] = expf(att[p] - mx); den += att[p]; }
    float inv = 1.f / den;
#pragma unroll
    for (int p = 0; p < 6; ++p) {
      float a = att[p] * inv;
      float off = sane(res[p] + ldx(offs_b, p, f32));
      off = fminf(fmaxf(off, 0.f), 31.f);
      float lo = floorf(off), hi = ceilf(off), fr = off - lo;
      int il = min(max((int)lo, 0), 31);
      int ih = min(max((int)hi, 0), 31);
      sm[il] += a * (1.f - fr);
      sm[ih] += a * fr;
    }
  }
  __syncthreads();
  if (lane < Z_) g_Mt[((bz >> 5) * Z_ + lane) * Z_ + (bz & 31)] = sm[lane];
}

// ------------------------------------------------ KB: z-mix of u + BN stats
// grid 9216 = b(2) * o(256) * hc(18); 256 thr = 4 waves.
// Wave w owns zo in [w*8, w*8+8); lane owns 2 hw (float2 loads, 8B/lane).
// u reads duplicated across the 4 waves -> L1 hits after first wave.
__global__ __launch_bounds__(256) void kB_mix(void* outp) {
  const int f32 = g_isf32;
  const int id = blockIdx.x;
  const int b = id / 4608;
  const int rem = id % 4608;
  const int o = rem / 18;
  const int hc = rem % 18;
  const int tid = threadIdx.x, w = tid >> 6, lane = tid & 63;
  const int hw = hc * 128 + lane * 2;
  const size_t ubase = (size_t)(b * C_ + o) * NSP + hw;
  const float* __restrict__ Mtb = g_Mt + (size_t)b * Z_ * Z_ + w * 8;

  float a0[8], a1[8];
#pragma unroll
  for (int r = 0; r < 8; ++r) { a0[r] = 0.f; a1[r] = 0.f; }

  for (int y = 0; y < Z_; ++y) {
    const float2 uv = *(const float2*)(g_u + ubase + (size_t)y * HW_);
    const float4 m0 = *(const float4*)(Mtb + y * Z_);       // wave-uniform
    const float4 m1 = *(const float4*)(Mtb + y * Z_ + 4);
    a0[0] = fmaf(m0.x, uv.x, a0[0]); a1[0] = fmaf(m0.x, uv.y, a1[0]);
    a0[1] = fmaf(m0.y, uv.x, a0[1]); a1[1] = fmaf(m0.y, uv.y, a1[1]);
    a0[2] = fmaf(m0.z, uv.x, a0[2]); a1[2] = fmaf(m0.z, uv.y, a1[2]);
    a0[3] = fmaf(m0.w, uv.x, a0[3]); a1[3] = fmaf(m0.w, uv.y, a1[3]);
    a0[4] = fmaf(m1.x, uv.x, a0[4]); a1[4] = fmaf(m1.x, uv.y, a1[4]);
    a0[5] = fmaf(m1.y, uv.x, a0[5]); a1[5] = fmaf(m1.y, uv.y, a1[5]);
    a0[6] = fmaf(m1.z, uv.x, a0[6]); a1[6] = fmaf(m1.z, uv.y, a1[6]);
    a0[7] = fmaf(m1.w, uv.x, a0[7]); a1[7] = fmaf(m1.w, uv.y, a1[7]);
  }

  float s = 0.f, ss = 0.f;
  const size_t obase = (size_t)(b * C_ + o) * NSP + hw;
#pragma unroll
  for (int r = 0; r < 8; ++r) {
    const float v0 = sane(a0[r]);
    const float v1 = sane(a1[r]);
    const size_t e = obase + (size_t)(w * 8 + r) * HW_;
    if (f32) {
      *(float2*)((float*)outp + e) = make_float2(v0, v1);
    } else {
      *(u32*)((u16*)outp + e) = (u32)f2bf(v0) | ((u32)f2bf(v1) << 16);
    }
    s += v0 + v1;
    ss += v0 * v0 + v1 * v1;
  }
  s = wredsum(s);
  ss = wredsum(ss);
  if (lane == 0) {
    atomicAdd(&g_bn_sum[o], s);
    atomicAdd(&g_bn_ssq[o], ss);
  }
}

// ------------------------------------------------ K5: BN + residual (vectorized)
__global__ __launch_bounds__(256) void k5_final(
    const void* f, void* outp, const void* gamma, const void* beta) {
  const int f32 = g_isf32;
  const size_t e4 = ((size_t)blockIdx.x * 256 + threadIdx.x) * 4;
  const int o = (int)((e4 / NSP) & 255);
  const float mean = g_bn_sum[o] * (1.f / NBN);
  const float var = fmaxf(g_bn_ssq[o] * (1.f / NBN) - mean * mean, 0.f);
  const float rstd = rsqrtf(var + 1e-5f);
  const float sc = ldx(gamma, o, f32) * rstd;
  const float sh = ldx(beta, o, f32) - mean * sc;
  if (f32) {
    float4 ov = *(float4*)((float*)outp + e4);
    const float4 fv = *(const float4*)((const float*)f + e4);
    ov.x = sane(ov.x * sc + sh + fv.x);
    ov.y = sane(ov.y * sc + sh + fv.y);
    ov.z = sane(ov.z * sc + sh + fv.z);
    ov.w = sane(ov.w * sc + sh + fv.w);
    *(float4*)((float*)outp + e4) = ov;
  } else {
    const ushort4 ov = *(const ushort4*)((const u16*)outp + e4);
    const ushort4 fv = *(const ushort4*)((const u16*)f + e4);
    ushort4 rv;
    rv.x = f2bf(sane(bf2f(ov.x) * sc + sh + bf2f(fv.x)));
    rv.y = f2bf(sane(bf2f(ov.y) * sc + sh + bf2f(fv.y)));
    rv.z = f2bf(sane(bf2f(ov.z) * sc + sh + bf2f(fv.z)));
    rv.w = f2bf(sane(bf2f(ov.w) * sc + sh + bf2f(fv.w)));
    *(ushort4*)((u16*)outp + e4) = rv;
  }
}

// ------------------------------------------------ launch
extern "C" void kernel_launch(void* const* d_in, const int* in_sizes, int n_in,
                              void* d_out, int out_size, void* d_ws, size_t ws_size,
                              hipStream_t stream)
{
  (void)in_sizes; (void)n_in; (void)out_size; (void)d_ws; (void)ws_size;
  const void* f      = d_in[0];
  const void* q_w    = d_in[1];
  const void* v_w    = d_in[2];
  const void* o_w    = d_in[3];
  const void* offs_w = d_in[4];
  const void* offs_b = d_in[5];
  const void* attn_w = d_in[6];
  const void* attn_b = d_in[7];
  const void* gamma  = d_in[8];
  const void* beta   = d_in[9];

  k00_detect<<<1, 64, 0, stream>>>(f);
  k0_setup<<<257, 256, 0, stream>>>(o_w, v_w, q_w);
  kP_probe<<<1, 512, 0, stream>>>(f);
  kA_mfma<<<2304, 512, 0, stream>>>(f);
  kA_gemm<<<4608, 256, 0, stream>>>(f);      // fallback, gated on g_use_mfma
  k2_mbuild<<<64, 64, 0, stream>>>(offs_w, offs_b, attn_w, attn_b);
  kB_mix<<<9216, 256, 0, stream>>>(d_out);
  k5_final<<<36864, 256, 0, stream>>>(f, d_out, gamma, beta);
}